// Round 25
// baseline (51.279 us; speedup 1.0000x reference)
//
#include <hip/hip_runtime.h>
#include <hip/hip_bf16.h>

typedef __attribute__((ext_vector_type(8))) __bf16 bf16x8;
typedef __attribute__((ext_vector_type(4))) float f32x4;
typedef __attribute__((ext_vector_type(8))) unsigned short ushort8;

__device__ __forceinline__ unsigned short f2bf(float f) {
  unsigned u = __builtin_bit_cast(unsigned, f);
  u += 0x7FFFu + ((u >> 16) & 1u);   // round-to-nearest-even
  return (unsigned short)(u >> 16);
}

__device__ __forceinline__ float bf2f(unsigned short h) {
  return __builtin_bit_cast(float, (unsigned)h << 16);
}

__device__ __forceinline__ void gload_lds16(const void* g, void* l) {
  __builtin_amdgcn_global_load_lds(
      (const __attribute__((address_space(1))) void*)g,
      (__attribute__((address_space(3))) void*)l, 16, 0, 0);
}

__device__ __forceinline__ void barrier_fence() {
  __builtin_amdgcn_s_barrier();
  asm volatile("" ::: "memory");
}

template <int N>
__device__ __forceinline__ void waitvm() {
  if constexpr (N == 0)      asm volatile("s_waitcnt vmcnt(0)" ::: "memory");
  else if constexpr (N == 8) asm volatile("s_waitcnt vmcnt(8)" ::: "memory");
}

// ---- prep: weight conversions (r22 verbatim) ----
// [0,2048)    : U[4096][512] -> Ut[512][4096] bf16 (transpose)
// [2048,2560) : W[1024][512] -> Wt[512][1024] bf16 (transpose)
// [2560,3584) : V   (2M f32) -> Vb bf16
__global__ __launch_bounds__(256) void prep_kernel(
    const float* __restrict__ U, unsigned short* __restrict__ Ut,
    const float* __restrict__ W, unsigned short* __restrict__ Wt,
    const float* __restrict__ V, unsigned short* __restrict__ Vb) {
  __shared__ float tile[32][33];
  const int b = blockIdx.x;
  const int tid = threadIdx.x;
  if (b < 2560) {
    const float* src;
    unsigned short* dst;
    int rows, cols, bx, by;
    if (b < 2048) {
      src = U; dst = Ut; rows = 4096; cols = 512;
      bx = (b & 15) * 32; by = (b >> 4) * 32;
    } else {
      int bb = b - 2048;
      src = W; dst = Wt; rows = 1024; cols = 512;
      bx = (bb & 15) * 32; by = (bb >> 4) * 32;
    }
    const int tx = tid & 31, ty = tid >> 5;
    for (int i = ty; i < 32; i += 8)
      tile[i][tx] = src[(size_t)(by + i) * cols + bx + tx];
    __syncthreads();
    for (int i = ty; i < 32; i += 8)
      dst[(size_t)(bx + i) * rows + by + tx] = f2bf(tile[tx][i]);
  } else {
    const size_t i = (size_t)(b - 2560) * 256 + tid;  // 8 f32 per thread
    const float4* s4 = reinterpret_cast<const float4*>(V) + 2 * i;
    float4 a = s4[0], c = s4[1];
    ushort8 o;
    o[0] = f2bf(a.x); o[1] = f2bf(a.y); o[2] = f2bf(a.z); o[3] = f2bf(a.w);
    o[4] = f2bf(c.x); o[5] = f2bf(c.y); o[6] = f2bf(c.z); o[7] = f2bf(c.w);
    *(reinterpret_cast<ushort8*>(Vb) + i) = o;
  }
}

// ======== bf16 GEMM core (gemm2): 128x128, counted-vmcnt DEPTH=2 ========
// A,Bt bf16 via global_load_lds.  COLMAP: XCD chunks advance along rows
// within a column stripe (each XCD touches 4 of 32 B-panels -> L2-local B).
// EPI 2: outf[idx] = relu(acc + e0[col]).
template <int FM, int FN, int EPI, int DEPTH, bool COLMAP>
__device__ __forceinline__ void gemm_core(
    const unsigned short* __restrict__ A, const unsigned short* __restrict__ Bt,
    int N, int lda, int kchunk, const float* __restrict__ e0,
    float* __restrict__ outf, int nwg, int bid) {
  constexpr int BM = 32 * FM, BN = 32 * FN, BK = 64;
  constexpr int AI = FM, BI = FN;
  constexpr int ISS = AI + BI;
  __shared__ unsigned short lds[DEPTH][(BM + BN) * BK];

  const int tid = threadIdx.x;
  const int wid = tid >> 6;
  const int lane = tid & 63;
  const int wr = wid >> 1, wc = wid & 1;

  const int swz = (bid & 7) * (nwg >> 3) + (bid >> 3);
  const int nbn = N / BN;
  int brow, bcol;
  if constexpr (COLMAP) {
    const int nbm = nwg / nbn;
    brow = (swz % nbm) * BM;
    bcol = (swz / nbm) * BN;
  } else {
    brow = (swz / nbn) * BM;
    bcol = (swz % nbn) * BN;
  }

  f32x4 zero = {0.f, 0.f, 0.f, 0.f};
  f32x4 acc[FM][FN];
#pragma unroll
  for (int m = 0; m < FM; ++m)
#pragma unroll
    for (int n = 0; n < FN; ++n) acc[m][n] = zero;

  const int lr = lane >> 3;
  const int swzc = ((lane & 7) ^ lr) * 8;
  const unsigned short* Agh = A + (size_t)(brow + wid * (BM / 4) + lr) * lda + swzc;
  const unsigned short* Bgh = Bt + (size_t)(bcol + wid * (BN / 4) + lr) * lda + swzc;

  const int frow = lane & 15;
  const int fhi = lane >> 4;

  const int nsteps = kchunk / BK;

  auto stage = [&](int b, int kofs) {
    unsigned short* AsW = lds[b] + wid * (BM / 4) * 64;
#pragma unroll
    for (int i = 0; i < AI; ++i)
      gload_lds16(Agh + kofs + (size_t)(8 * i) * lda, AsW + i * 512);
    unsigned short* BsW = lds[b] + BM * BK + wid * (BN / 4) * 64;
#pragma unroll
    for (int i = 0; i < BI; ++i)
      gload_lds16(Bgh + kofs + (size_t)(8 * i) * lda, BsW + i * 512);
  };

  auto compute = [&](int cur) {
    const unsigned short* As = lds[cur];
    const unsigned short* Bs = lds[cur] + BM * BK;
#pragma unroll
    for (int ks = 0; ks < 2; ++ks) {
      bf16x8 af[FM], bg[FN];
#pragma unroll
      for (int m = 0; m < FM; ++m) {
        int row = wr * FM * 16 + m * 16 + frow;
        int pc = (ks * 4 + fhi) ^ (row & 7);
        af[m] = *reinterpret_cast<const bf16x8*>(As + row * 64 + pc * 8);
      }
#pragma unroll
      for (int n = 0; n < FN; ++n) {
        int row = wc * FN * 16 + n * 16 + frow;
        int pc = (ks * 4 + fhi) ^ (row & 7);
        bg[n] = *reinterpret_cast<const bf16x8*>(Bs + row * 64 + pc * 8);
      }
#pragma unroll
      for (int m = 0; m < FM; ++m)
#pragma unroll
        for (int n = 0; n < FN; ++n)
          acc[m][n] = __builtin_amdgcn_mfma_f32_16x16x32_bf16(af[m], bg[n],
                                                              acc[m][n], 0, 0, 0);
    }
  };

#pragma unroll
  for (int d = 0; d < DEPTH; ++d) stage(d, d * BK);

  int cur = 0;
  for (int t = 0; t < nsteps; ++t) {
    const int ahead = nsteps - 1 - t;
    if (ahead >= DEPTH - 1)
      waitvm<(DEPTH - 1) * ISS>();
    else
      waitvm<0>();
    barrier_fence();
    compute(cur);
    if (t + 1 < nsteps) {
      asm volatile("s_waitcnt lgkmcnt(0)" ::: "memory");
      barrier_fence();
      if (t + DEPTH < nsteps) stage(cur, (t + DEPTH) * BK);
    }
    cur = (cur + 1 == DEPTH) ? 0 : cur + 1;
  }

#pragma unroll
  for (int m = 0; m < FM; ++m) {
    int gr0 = brow + wr * FM * 16 + m * 16 + fhi * 4;
#pragma unroll
    for (int n = 0; n < FN; ++n) {
      int gc = bcol + wc * FN * 16 + n * 16 + frow;
#pragma unroll
      for (int j = 0; j < 4; ++j) {
        size_t idx = (size_t)(gr0 + j) * N + gc;
        float v = acc[m][n][j];
        if constexpr (EPI == 2) {
          v += e0[gc];
          outf[idx] = v > 0.f ? v : 0.f;
        } else {
          outf[idx] = v;
        }
      }
    }
  }
}

// ======== f32-A GEMM core (gemm01): 128x64 tile, 3 blocks/CU ====
// Same r19/r22 step schedule; tile narrowed to BN=64 so LDS = 2 x 24 KB
// -> 3 blocks/CU co-resident (cross-block TLP covers the per-step drain).
// 4 waves: wave block = 64x32, acc[4][2] (16 MFMA/step/wave).
// A f32 -> regs -> f2bf -> ds_write; B bf16 via global_load_lds (2 issues).
// Step t: bload(t+1) | compute(t) | vmcnt(0) | awrite(t+1) | aload(t+2) |
// lgkm(0) | barrier.  NON-TEMPLATE, single call site (one 48 KB LDS alloc).
// ROWMAP position map (A-panel XCD-L2 reuse).  nwg = 128 positions/split.
// Epilogue: outb[idx] = bf16(acc)  (split-K partial in bf16).
__device__ __forceinline__ void gemm_core_f32a(
    const float* __restrict__ A, const unsigned short* __restrict__ Bt,
    int lda, int kchunk, unsigned short* __restrict__ outb, int bid) {
  constexpr int N = 512;
  constexpr int BM = 128, BN = 64, BK = 64;
  constexpr int AELEM = BM * BK;                    // 8192 bf16 = 16 KB
  __shared__ unsigned short lds[2][AELEM + BN * BK];  // 2 x 24 KB

  const int tid = threadIdx.x;
  const int wid = tid >> 6;
  const int lane = tid & 63;
  const int wr = wid >> 1, wc = wid & 1;

  const int swz = (bid & 7) * 16 + (bid >> 3);      // nwg = 128
  const int nbn = N / BN;                           // 8
  const int brow = (swz / nbn) * BM;                // ROWMAP
  const int bcol = (swz % nbn) * BN;

  f32x4 zero = {0.f, 0.f, 0.f, 0.f};
  f32x4 acc[4][2];
#pragma unroll
  for (int m = 0; m < 4; ++m)
#pragma unroll
    for (int n = 0; n < 2; ++n) acc[m][n] = zero;

  const int lr = lane >> 3;      // 0..7
  const int lc = lane & 7;       // phys 16B chunk
  const int swzc = (lc ^ lr) * 8;
  const float* Agf = A + (size_t)(brow + wid * 32 + lr) * lda + swzc;
  const unsigned short* Bgh = Bt + (size_t)(bcol + wid * 16 + lr) * lda + swzc;

  const int frow = lane & 15;
  const int fhi = lane >> 4;

  const int nsteps = kchunk / BK;  // 16 or 8

  float4 areg[4][2];
  auto aload = [&](int kofs) {     // 8 dwordx4 / wave (A rows wid*32..+31)
#pragma unroll
    for (int i = 0; i < 4; ++i) {
      const float* s = Agf + kofs + (size_t)(8 * i) * lda;
      areg[i][0] = *reinterpret_cast<const float4*>(s);
      areg[i][1] = *reinterpret_cast<const float4*>(s + 4);
    }
  };
  auto awrite = [&](int b) {
    unsigned short* AsW = lds[b] + wid * 2048 + lane * 8;
#pragma unroll
    for (int i = 0; i < 4; ++i) {
      float4 x = areg[i][0], y = areg[i][1];
      ushort8 o;
      o[0] = f2bf(x.x); o[1] = f2bf(x.y); o[2] = f2bf(x.z); o[3] = f2bf(x.w);
      o[4] = f2bf(y.x); o[5] = f2bf(y.y); o[6] = f2bf(y.z); o[7] = f2bf(y.w);
      *reinterpret_cast<ushort8*>(AsW + i * 512) = o;
    }
  };
  auto bload = [&](int b, int kofs) {  // 2 gload_lds / wave (B rows wid*16..+15)
    unsigned short* BsW = lds[b] + AELEM + wid * 1024;
#pragma unroll
    for (int i = 0; i < 2; ++i)
      gload_lds16(Bgh + kofs + (size_t)(8 * i) * lda, BsW + i * 512);
  };

  auto compute = [&](int cur) {
    const unsigned short* As = lds[cur];
    const unsigned short* Bs = lds[cur] + AELEM;
#pragma unroll
    for (int ks = 0; ks < 2; ++ks) {
      bf16x8 af[4], bg[2];
#pragma unroll
      for (int m = 0; m < 4; ++m) {
        int row = wr * 64 + m * 16 + frow;
        int pc = (ks * 4 + fhi) ^ (row & 7);
        af[m] = *reinterpret_cast<const bf16x8*>(As + row * 64 + pc * 8);
      }
#pragma unroll
      for (int n = 0; n < 2; ++n) {
        int row = wc * 32 + n * 16 + frow;
        int pc = (ks * 4 + fhi) ^ (row & 7);
        bg[n] = *reinterpret_cast<const bf16x8*>(Bs + row * 64 + pc * 8);
      }
#pragma unroll
      for (int m = 0; m < 4; ++m)
#pragma unroll
        for (int n = 0; n < 2; ++n)
          acc[m][n] = __builtin_amdgcn_mfma_f32_16x16x32_bf16(af[m], bg[n],
                                                              acc[m][n], 0, 0, 0);
    }
  };

  // prologue: A(0)+B(0) staged & written; A(1) in flight to regs
  aload(0);
  bload(0, 0);
  waitvm<0>();
  awrite(0);
  aload(BK);
  asm volatile("s_waitcnt lgkmcnt(0)" ::: "memory");
  barrier_fence();

  for (int t = 0; t < nsteps; ++t) {
    const int cur = t & 1;
    if (t + 1 < nsteps) bload(cur ^ 1, (t + 1) * BK);
    compute(cur);
    if (t + 1 < nsteps) {
      waitvm<0>();     // my A(t+1) regs + my B(t+1) portion landed
      awrite(cur ^ 1);
      if (t + 2 < nsteps) aload((t + 2) * BK);
      asm volatile("s_waitcnt lgkmcnt(0)" ::: "memory");
      barrier_fence();
    }
  }

  // epilogue: bf16 partial write
#pragma unroll
  for (int m = 0; m < 4; ++m) {
    int gr0 = brow + wr * 64 + m * 16 + fhi * 4;
#pragma unroll
    for (int n = 0; n < 2; ++n) {
      int gc = bcol + wc * 32 + n * 16 + frow;
#pragma unroll
      for (int j = 0; j < 4; ++j)
        outb[(size_t)(gr0 + j) * N + gc] = f2bf(acc[m][n][j]);
    }
  }
}

// ---- merged split-K partial GEMMs, 128x64 tiles, ONE call site ----
// blocks [0,512)   : inputs@U  split-4 (lda 4096, kchunk 1024) -> p1b[4]
// blocks [512,768) : context@W split-2 (lda 1024, kchunk  512) -> p0b[2]
// 128 positions per split; 768 blocks = 3/CU uniform.
__global__ __launch_bounds__(256) void gemm01_kernel(
    const float* __restrict__ inp, const unsigned short* __restrict__ Ut,
    const float* __restrict__ ctx, const unsigned short* __restrict__ Wt,
    unsigned short* __restrict__ p0b, unsigned short* __restrict__ p1b) {
  const int bid = (int)blockIdx.x;
  constexpr size_t MN = (size_t)2048 * 512;
  const float* A;
  const unsigned short* Bt;
  int lda, kchunk, lbid;
  unsigned short* outp;
  if (bid < 512) {
    const int split = bid >> 7;          // 4 splits x 128 positions
    A = inp + (size_t)split * 1024;
    Bt = Ut + (size_t)split * 1024;
    lda = 4096; kchunk = 1024; outp = p1b + split * MN; lbid = bid & 127;
  } else {
    const int sb = bid - 512;
    const int split = sb >> 7;           // 2 splits x 128 positions
    A = ctx + (size_t)split * 512;
    Bt = Wt + (size_t)split * 512;
    lda = 1024; kchunk = 512; outp = p0b + split * MN; lbid = sb & 127;
  }
  gemm_core_f32a(A, Bt, lda, kchunk, outp, lbid);
}

// ---- final GEMM: out = relu(xus @ V^T + bias), 128x128, COLMAP ----
__global__ __launch_bounds__(256) void gemm2_kernel(
    const unsigned short* __restrict__ xus, const unsigned short* __restrict__ Vb,
    const float* __restrict__ bias, float* __restrict__ out) {
  gemm_core<4, 4, 2, 2, true>(xus, Vb, 4096, 512, 512, bias, out, 512,
                              (int)blockIdx.x);
}

// ---- fused split-K reduce (bf16 partials): xus = bf16((sum p1) * (S + sum p0))
__global__ void reduce_mul_kernel(const unsigned short* __restrict__ p1,  // [4][MN]
                                  const unsigned short* __restrict__ p0,  // [2][MN]
                                  const float* __restrict__ Svec,         // [512]
                                  unsigned short* __restrict__ xus, int MN) {
  int i = blockIdx.x * blockDim.x + threadIdx.x;
  size_t base = (size_t)i * 8;
  if (base >= (size_t)MN) return;
  float xu[8] = {0.f, 0.f, 0.f, 0.f, 0.f, 0.f, 0.f, 0.f};
#pragma unroll
  for (int k = 0; k < 4; ++k) {
    ushort8 a = *reinterpret_cast<const ushort8*>(p1 + (size_t)k * MN + base);
#pragma unroll
    for (int j = 0; j < 8; ++j) xu[j] += bf2f(a[j]);
  }
  ushort8 s0 = *reinterpret_cast<const ushort8*>(p0 + base);
  ushort8 s1 = *reinterpret_cast<const ushort8*>(p0 + (size_t)MN + base);
  const float* sv = Svec + (base & 511);   // base%8==0, no wrap within 8
  ushort8 o;
#pragma unroll
  for (int j = 0; j < 8; ++j) {
    float s = bf2f(s0[j]) + bf2f(s1[j]) + sv[j];
    o[j] = f2bf(xu[j] * s);
  }
  *reinterpret_cast<ushort8*>(xus + base) = o;
}

extern "C" void kernel_launch(void* const* d_in, const int* in_sizes, int n_in,
                              void* d_out, int out_size, void* d_ws, size_t ws_size,
                              hipStream_t stream) {
  constexpr int Bm = 2048, Nn = 4096, Cc = 1024, UU = 4096, RR = 512;
  const float* inputs  = (const float*)d_in[0];
  const float* context = (const float*)d_in[1];
  const float* U       = (const float*)d_in[2];
  const float* S       = (const float*)d_in[3];
  const float* V       = (const float*)d_in[4];
  const float* W       = (const float*)d_in[5];
  const float* bias    = (const float*)d_in[6];
  float* out = (float*)d_out;

  char* p = (char*)d_ws;
  unsigned short* Ut   = (unsigned short*)p; p += (size_t)RR * Nn * 2;      //  4 MB
  unsigned short* Wt   = (unsigned short*)p; p += (size_t)RR * Cc * 2;      //  1 MB
  unsigned short* Vb   = (unsigned short*)p; p += (size_t)UU * RR * 2;      //  4 MB
  unsigned short* p0b  = (unsigned short*)p; p += (size_t)2 * Bm * RR * 2;  //  4 MB
  unsigned short* p1b  = (unsigned short*)p; p += (size_t)4 * Bm * RR * 2;  //  8 MB
  unsigned short* xus  = (unsigned short*)p; p += (size_t)Bm * RR * 2;      //  2 MB

  // 1) prep: U^T, W^T, V -> bf16
  prep_kernel<<<3584, 256, 0, stream>>>(U, Ut, W, Wt, V, Vb);

  // 2) merged split-K partials from f32 A (128x64 tiles, 3 blocks/CU)
  gemm01_kernel<<<768, 256, 0, stream>>>(inputs, Ut, context, Wt, p0b, p1b);

  // 3) xus = bf16((sum p1) * (S + sum p0))   (bf16 partials)
  reduce_mul_kernel<<<Bm * RR / 8 / 256, 256, 0, stream>>>(p1b, p0b, S, xus, Bm * RR);

  // 4) out = relu(xus @ V^T + bias)   (128x128 tiles, col-chunked XCD map)
  gemm2_kernel<<<512, 256, 0, stream>>>(xus, Vb, bias, out);
}

// Round 26
// 50.486 us; speedup vs baseline: 1.0157x; 1.0157x over previous
//
#include <hip/hip_runtime.h>
#include <hip/hip_bf16.h>

typedef __attribute__((ext_vector_type(8))) __bf16 bf16x8;
typedef __attribute__((ext_vector_type(4))) float f32x4;
typedef __attribute__((ext_vector_type(8))) unsigned short ushort8;

__device__ __forceinline__ unsigned short f2bf(float f) {
  unsigned u = __builtin_bit_cast(unsigned, f);
  u += 0x7FFFu + ((u >> 16) & 1u);   // round-to-nearest-even
  return (unsigned short)(u >> 16);
}

__device__ __forceinline__ float bf2f(unsigned short h) {
  return __builtin_bit_cast(float, (unsigned)h << 16);
}

__device__ __forceinline__ void gload_lds16(const void* g, void* l) {
  __builtin_amdgcn_global_load_lds(
      (const __attribute__((address_space(1))) void*)g,
      (__attribute__((address_space(3))) void*)l, 16, 0, 0);
}

__device__ __forceinline__ void barrier_fence() {
  __builtin_amdgcn_s_barrier();
  asm volatile("" ::: "memory");
}

template <int N>
__device__ __forceinline__ void waitvm() {
  if constexpr (N == 0)      asm volatile("s_waitcnt vmcnt(0)" ::: "memory");
  else if constexpr (N == 8) asm volatile("s_waitcnt vmcnt(8)" ::: "memory");
}

// ---- prep: weight conversions only ----
// [0,2048)    : U[4096][512] -> Ut[512][4096] bf16 (transpose)
// [2048,2560) : W[1024][512] -> Wt[512][1024] bf16 (transpose)
// [2560,3584) : V   (2M f32) -> Vb bf16
__global__ __launch_bounds__(256) void prep_kernel(
    const float* __restrict__ U, unsigned short* __restrict__ Ut,
    const float* __restrict__ W, unsigned short* __restrict__ Wt,
    const float* __restrict__ V, unsigned short* __restrict__ Vb) {
  __shared__ float tile[32][33];
  const int b = blockIdx.x;
  const int tid = threadIdx.x;
  if (b < 2560) {
    const float* src;
    unsigned short* dst;
    int rows, cols, bx, by;
    if (b < 2048) {
      src = U; dst = Ut; rows = 4096; cols = 512;
      bx = (b & 15) * 32; by = (b >> 4) * 32;
    } else {
      int bb = b - 2048;
      src = W; dst = Wt; rows = 1024; cols = 512;
      bx = (bb & 15) * 32; by = (bb >> 4) * 32;
    }
    const int tx = tid & 31, ty = tid >> 5;
    for (int i = ty; i < 32; i += 8)
      tile[i][tx] = src[(size_t)(by + i) * cols + bx + tx];
    __syncthreads();
    for (int i = ty; i < 32; i += 8)
      dst[(size_t)(bx + i) * rows + by + tx] = f2bf(tile[tx][i]);
  } else {
    const size_t i = (size_t)(b - 2560) * 256 + tid;  // 8 f32 per thread
    const float4* s4 = reinterpret_cast<const float4*>(V) + 2 * i;
    float4 a = s4[0], c = s4[1];
    ushort8 o;
    o[0] = f2bf(a.x); o[1] = f2bf(a.y); o[2] = f2bf(a.z); o[3] = f2bf(a.w);
    o[4] = f2bf(c.x); o[5] = f2bf(c.y); o[6] = f2bf(c.z); o[7] = f2bf(c.w);
    *(reinterpret_cast<ushort8*>(Vb) + i) = o;
  }
}

// ======== bf16 GEMM core (gemm2): 128x128, counted-vmcnt DEPTH=2 ========
// A,Bt bf16 via global_load_lds.  COLMAP: XCD chunks advance along rows
// within a column stripe (each XCD touches 4 of 32 B-panels -> L2-local B;
// B is gemm2's larger re-read operand).
// EPI 2: outf[idx] = relu(acc + e0[col]).
template <int FM, int FN, int EPI, int DEPTH, bool COLMAP>
__device__ __forceinline__ void gemm_core(
    const unsigned short* __restrict__ A, const unsigned short* __restrict__ Bt,
    int N, int lda, int kchunk, const float* __restrict__ e0,
    float* __restrict__ outf, int nwg, int bid) {
  constexpr int BM = 32 * FM, BN = 32 * FN, BK = 64;
  constexpr int AI = FM, BI = FN;
  constexpr int ISS = AI + BI;
  __shared__ unsigned short lds[DEPTH][(BM + BN) * BK];

  const int tid = threadIdx.x;
  const int wid = tid >> 6;
  const int lane = tid & 63;
  const int wr = wid >> 1, wc = wid & 1;

  const int swz = (bid & 7) * (nwg >> 3) + (bid >> 3);
  const int nbn = N / BN;
  int brow, bcol;
  if constexpr (COLMAP) {
    const int nbm = nwg / nbn;
    brow = (swz % nbm) * BM;
    bcol = (swz / nbm) * BN;
  } else {
    brow = (swz / nbn) * BM;
    bcol = (swz % nbn) * BN;
  }

  f32x4 zero = {0.f, 0.f, 0.f, 0.f};
  f32x4 acc[FM][FN];
#pragma unroll
  for (int m = 0; m < FM; ++m)
#pragma unroll
    for (int n = 0; n < FN; ++n) acc[m][n] = zero;

  const int lr = lane >> 3;
  const int swzc = ((lane & 7) ^ lr) * 8;
  const unsigned short* Agh = A + (size_t)(brow + wid * (BM / 4) + lr) * lda + swzc;
  const unsigned short* Bgh = Bt + (size_t)(bcol + wid * (BN / 4) + lr) * lda + swzc;

  const int frow = lane & 15;
  const int fhi = lane >> 4;

  const int nsteps = kchunk / BK;

  auto stage = [&](int b, int kofs) {
    unsigned short* AsW = lds[b] + wid * (BM / 4) * 64;
#pragma unroll
    for (int i = 0; i < AI; ++i)
      gload_lds16(Agh + kofs + (size_t)(8 * i) * lda, AsW + i * 512);
    unsigned short* BsW = lds[b] + BM * BK + wid * (BN / 4) * 64;
#pragma unroll
    for (int i = 0; i < BI; ++i)
      gload_lds16(Bgh + kofs + (size_t)(8 * i) * lda, BsW + i * 512);
  };

  auto compute = [&](int cur) {
    const unsigned short* As = lds[cur];
    const unsigned short* Bs = lds[cur] + BM * BK;
#pragma unroll
    for (int ks = 0; ks < 2; ++ks) {
      bf16x8 af[FM], bg[FN];
#pragma unroll
      for (int m = 0; m < FM; ++m) {
        int row = wr * FM * 16 + m * 16 + frow;
        int pc = (ks * 4 + fhi) ^ (row & 7);
        af[m] = *reinterpret_cast<const bf16x8*>(As + row * 64 + pc * 8);
      }
#pragma unroll
      for (int n = 0; n < FN; ++n) {
        int row = wc * FN * 16 + n * 16 + frow;
        int pc = (ks * 4 + fhi) ^ (row & 7);
        bg[n] = *reinterpret_cast<const bf16x8*>(Bs + row * 64 + pc * 8);
      }
#pragma unroll
      for (int m = 0; m < FM; ++m)
#pragma unroll
        for (int n = 0; n < FN; ++n)
          acc[m][n] = __builtin_amdgcn_mfma_f32_16x16x32_bf16(af[m], bg[n],
                                                              acc[m][n], 0, 0, 0);
    }
  };

#pragma unroll
  for (int d = 0; d < DEPTH; ++d) stage(d, d * BK);

  int cur = 0;
  for (int t = 0; t < nsteps; ++t) {
    const int ahead = nsteps - 1 - t;
    if (ahead >= DEPTH - 1)
      waitvm<(DEPTH - 1) * ISS>();
    else
      waitvm<0>();
    barrier_fence();
    compute(cur);
    if (t + 1 < nsteps) {
      asm volatile("s_waitcnt lgkmcnt(0)" ::: "memory");
      barrier_fence();
      if (t + DEPTH < nsteps) stage(cur, (t + DEPTH) * BK);
    }
    cur = (cur + 1 == DEPTH) ? 0 : cur + 1;
  }

#pragma unroll
  for (int m = 0; m < FM; ++m) {
    int gr0 = brow + wr * FM * 16 + m * 16 + fhi * 4;
#pragma unroll
    for (int n = 0; n < FN; ++n) {
      int gc = bcol + wc * FN * 16 + n * 16 + frow;
#pragma unroll
      for (int j = 0; j < 4; ++j) {
        size_t idx = (size_t)(gr0 + j) * N + gc;
        float v = acc[m][n][j];
        if constexpr (EPI == 2) {
          v += e0[gc];
          outf[idx] = v > 0.f ? v : 0.f;
        } else {
          outf[idx] = v;
        }
      }
    }
  }
}

// ======== f32-A GEMM core (gemm01): r14/r19 schedule, ROWMAP ====
// ROWMAP: consecutive swz (same XCD) share the A-panel — A (f32, 512 KB/panel)
// is gemm01's larger re-read operand.
// A f32 -> regs -> f2bf -> ds_write (fused cvt); B bf16 via global_load_lds.
// Step t: bload(t+1) | compute(t) | vmcnt(0) | awrite(t+1) | aload(t+2) |
// lgkm(0) | barrier.  NON-TEMPLATE, single call site (one 64 KB LDS alloc).
// Epilogue: outb[idx] = bf16(acc)  (split-K partial in bf16).
__device__ __forceinline__ void gemm_core_f32a(
    const float* __restrict__ A, const unsigned short* __restrict__ Bt,
    int lda, int kchunk, unsigned short* __restrict__ outb, int nwg, int bid) {
  constexpr int N = 512;
  constexpr int BM = 128, BN = 128, BK = 64;
  __shared__ unsigned short lds[2][(BM + BN) * BK];  // 2 x 32 KB

  const int tid = threadIdx.x;
  const int wid = tid >> 6;
  const int lane = tid & 63;
  const int wr = wid >> 1, wc = wid & 1;

  const int swz = (bid & 7) * (nwg >> 3) + (bid >> 3);
  const int nbn = N / BN;        // 4
  const int brow = (swz / nbn) * BM;
  const int bcol = (swz % nbn) * BN;

  f32x4 zero = {0.f, 0.f, 0.f, 0.f};
  f32x4 acc[4][4];
#pragma unroll
  for (int m = 0; m < 4; ++m)
#pragma unroll
    for (int n = 0; n < 4; ++n) acc[m][n] = zero;

  const int lr = lane >> 3;      // 0..7
  const int lc = lane & 7;       // phys 16B chunk
  const int swzc = (lc ^ lr) * 8;
  const float* Agf = A + (size_t)(brow + wid * 32 + lr) * lda + swzc;
  const unsigned short* Bgh = Bt + (size_t)(bcol + wid * 32 + lr) * lda + swzc;

  const int frow = lane & 15;
  const int fhi = lane >> 4;

  const int nsteps = kchunk / BK;  // 16 or 8

  float4 areg[4][2];
  auto aload = [&](int kofs) {
#pragma unroll
    for (int i = 0; i < 4; ++i) {
      const float* s = Agf + kofs + (size_t)(8 * i) * lda;
      areg[i][0] = *reinterpret_cast<const float4*>(s);
      areg[i][1] = *reinterpret_cast<const float4*>(s + 4);
    }
  };
  auto awrite = [&](int b) {
    unsigned short* AsW = lds[b] + wid * 2048 + lane * 8;
#pragma unroll
    for (int i = 0; i < 4; ++i) {
      float4 x = areg[i][0], y = areg[i][1];
      ushort8 o;
      o[0] = f2bf(x.x); o[1] = f2bf(x.y); o[2] = f2bf(x.z); o[3] = f2bf(x.w);
      o[4] = f2bf(y.x); o[5] = f2bf(y.y); o[6] = f2bf(y.z); o[7] = f2bf(y.w);
      *reinterpret_cast<ushort8*>(AsW + i * 512) = o;
    }
  };
  auto bload = [&](int b, int kofs) {
    unsigned short* BsW = lds[b] + BM * BK + wid * 2048;
#pragma unroll
    for (int i = 0; i < 4; ++i)
      gload_lds16(Bgh + kofs + (size_t)(8 * i) * lda, BsW + i * 512);
  };

  auto compute = [&](int cur) {
    const unsigned short* As = lds[cur];
    const unsigned short* Bs = lds[cur] + BM * BK;
#pragma unroll
    for (int ks = 0; ks < 2; ++ks) {
      bf16x8 af[4], bg[4];
#pragma unroll
      for (int m = 0; m < 4; ++m) {
        int row = wr * 64 + m * 16 + frow;
        int pc = (ks * 4 + fhi) ^ (row & 7);
        af[m] = *reinterpret_cast<const bf16x8*>(As + row * 64 + pc * 8);
      }
#pragma unroll
      for (int n = 0; n < 4; ++n) {
        int row = wc * 64 + n * 16 + frow;
        int pc = (ks * 4 + fhi) ^ (row & 7);
        bg[n] = *reinterpret_cast<const bf16x8*>(Bs + row * 64 + pc * 8);
      }
#pragma unroll
      for (int m = 0; m < 4; ++m)
#pragma unroll
        for (int n = 0; n < 4; ++n)
          acc[m][n] = __builtin_amdgcn_mfma_f32_16x16x32_bf16(af[m], bg[n],
                                                              acc[m][n], 0, 0, 0);
    }
  };

  // prologue: A(0)+B(0) staged & written; A(1) in flight to regs
  aload(0);
  bload(0, 0);
  waitvm<0>();
  awrite(0);
  aload(BK);
  asm volatile("s_waitcnt lgkmcnt(0)" ::: "memory");
  barrier_fence();

  for (int t = 0; t < nsteps; ++t) {
    const int cur = t & 1;
    if (t + 1 < nsteps) bload(cur ^ 1, (t + 1) * BK);
    compute(cur);
    if (t + 1 < nsteps) {
      waitvm<0>();     // my A(t+1) regs + my B(t+1) portion landed
      awrite(cur ^ 1);
      if (t + 2 < nsteps) aload((t + 2) * BK);
      asm volatile("s_waitcnt lgkmcnt(0)" ::: "memory");
      barrier_fence();
    }
  }

  // epilogue: bf16 partial write
#pragma unroll
  for (int m = 0; m < 4; ++m) {
    int gr0 = brow + wr * 64 + m * 16 + fhi * 4;
#pragma unroll
    for (int n = 0; n < 4; ++n) {
      int gc = bcol + wc * 64 + n * 16 + frow;
#pragma unroll
      for (int j = 0; j < 4; ++j)
        outb[(size_t)(gr0 + j) * N + gc] = f2bf(acc[m][n][j]);
    }
  }
}

// ---- merged split-K partial GEMMs, ONE call site ----
// blocks [0,256)   : inputs@U  split-4 (lda 4096, kchunk 1024) -> p1b[4]
// blocks [256,384) : context@W split-2 (lda 1024, kchunk  512) -> p0b[2]
__global__ __launch_bounds__(256) void gemm01_kernel(
    const float* __restrict__ inp, const unsigned short* __restrict__ Ut,
    const float* __restrict__ ctx, const unsigned short* __restrict__ Wt,
    unsigned short* __restrict__ p0b, unsigned short* __restrict__ p1b) {
  const int bid = (int)blockIdx.x;
  constexpr size_t MN = (size_t)2048 * 512;
  const float* A;
  const unsigned short* Bt;
  int lda, kchunk, lbid;
  unsigned short* outp;
  if (bid < 256) {
    const int split = bid >> 6;          // 4 splits x 64 positions
    A = inp + (size_t)split * 1024;
    Bt = Ut + (size_t)split * 1024;
    lda = 4096; kchunk = 1024; outp = p1b + split * MN; lbid = bid & 63;
  } else {
    const int sb = bid - 256;
    const int split = sb >> 6;           // 2 splits x 64 positions
    A = ctx + (size_t)split * 512;
    Bt = Wt + (size_t)split * 512;
    lda = 1024; kchunk = 512; outp = p0b + split * MN; lbid = sb & 63;
  }
  gemm_core_f32a(A, Bt, lda, kchunk, outp, 64, lbid);
}

// ---- final GEMM: out = relu(xus @ V^T + bias), 128x128, COLMAP ----
__global__ __launch_bounds__(256) void gemm2_kernel(
    const unsigned short* __restrict__ xus, const unsigned short* __restrict__ Vb,
    const float* __restrict__ bias, float* __restrict__ out) {
  gemm_core<4, 4, 2, 2, true>(xus, Vb, 4096, 512, 512, bias, out, 512,
                              (int)blockIdx.x);
}

// ---- fused split-K reduce (bf16 partials): xus = bf16((sum p1) * (S + sum p0))
__global__ void reduce_mul_kernel(const unsigned short* __restrict__ p1,  // [4][MN]
                                  const unsigned short* __restrict__ p0,  // [2][MN]
                                  const float* __restrict__ Svec,         // [512]
                                  unsigned short* __restrict__ xus, int MN) {
  int i = blockIdx.x * blockDim.x + threadIdx.x;
  size_t base = (size_t)i * 8;
  if (base >= (size_t)MN) return;
  float xu[8] = {0.f, 0.f, 0.f, 0.f, 0.f, 0.f, 0.f, 0.f};
#pragma unroll
  for (int k = 0; k < 4; ++k) {
    ushort8 a = *reinterpret_cast<const ushort8*>(p1 + (size_t)k * MN + base);
#pragma unroll
    for (int j = 0; j < 8; ++j) xu[j] += bf2f(a[j]);
  }
  ushort8 s0 = *reinterpret_cast<const ushort8*>(p0 + base);
  ushort8 s1 = *reinterpret_cast<const ushort8*>(p0 + (size_t)MN + base);
  const float* sv = Svec + (base & 511);   // base%8==0, no wrap within 8
  ushort8 o;
#pragma unroll
  for (int j = 0; j < 8; ++j) {
    float s = bf2f(s0[j]) + bf2f(s1[j]) + sv[j];
    o[j] = f2bf(xu[j] * s);
  }
  *reinterpret_cast<ushort8*>(xus + base) = o;
}

extern "C" void kernel_launch(void* const* d_in, const int* in_sizes, int n_in,
                              void* d_out, int out_size, void* d_ws, size_t ws_size,
                              hipStream_t stream) {
  constexpr int Bm = 2048, Nn = 4096, Cc = 1024, UU = 4096, RR = 512;
  const float* inputs  = (const float*)d_in[0];
  const float* context = (const float*)d_in[1];
  const float* U       = (const float*)d_in[2];
  const float* S       = (const float*)d_in[3];
  const float* V       = (const float*)d_in[4];
  const float* W       = (const float*)d_in[5];
  const float* bias    = (const float*)d_in[6];
  float* out = (float*)d_out;

  char* p = (char*)d_ws;
  unsigned short* Ut   = (unsigned short*)p; p += (size_t)RR * Nn * 2;      //  4 MB
  unsigned short* Wt   = (unsigned short*)p; p += (size_t)RR * Cc * 2;      //  1 MB
  unsigned short* Vb   = (unsigned short*)p; p += (size_t)UU * RR * 2;      //  4 MB
  unsigned short* p0b  = (unsigned short*)p; p += (size_t)2 * Bm * RR * 2;  //  4 MB
  unsigned short* p1b  = (unsigned short*)p; p += (size_t)4 * Bm * RR * 2;  //  8 MB
  unsigned short* xus  = (unsigned short*)p; p += (size_t)Bm * RR * 2;      //  2 MB

  // 1) prep: U^T, W^T, V -> bf16 (inputs/context conversion fused into gemm01)
  prep_kernel<<<3584, 256, 0, stream>>>(U, Ut, W, Wt, V, Vb);

  // 2) merged split-K partials from f32 A (128x128 tiles, fused cvt, bf16 out)
  gemm01_kernel<<<384, 256, 0, stream>>>(inputs, Ut, context, Wt, p0b, p1b);

  // 3) xus = bf16((sum p1) * (S + sum p0))   (bf16 partials)
  reduce_mul_kernel<<<Bm * RR / 8 / 256, 256, 0, stream>>>(p1b, p0b, S, xus, Bm * RR);

  // 4) out = relu(xus @ V^T + bias)   (128x128 tiles, col-chunked XCD map)
  gemm2_kernel<<<512, 256, 0, stream>>>(xus, Vb, bias, out);
}